// Round 13
// baseline (917.331 us; speedup 1.0000x reference)
//
#include <hip/hip_runtime.h>
#include <cstdint>
#include <cstddef>

#define DEVFN static __device__ __forceinline__

typedef __attribute__((ext_vector_type(8))) short shortx8;   // 8 bf16 (4 VGPRs)
typedef __attribute__((ext_vector_type(4))) float floatx4;   // 4 f32

DEVFN float bf2f(unsigned short u) {
  union { unsigned int i; float f; } v; v.i = ((unsigned int)u) << 16; return v.f;
}
DEVFN unsigned short f2bf(float f) {
  union { float f; unsigned int i; } v; v.f = f;
  unsigned int r = v.i + 0x7FFFu + ((v.i >> 16) & 1u);
  return (unsigned short)(r >> 16);
}

DEVFN void gload_lds16(const void* g, void* l) {
  __builtin_amdgcn_global_load_lds(
      (const __attribute__((address_space(1))) void*)(uintptr_t)g,
      (__attribute__((address_space(3))) void*)(uint32_t)(uintptr_t)l,
      16, 0, 0);
}

// ---------------- CSR build: dst-range ownership, LDS-only atomics ----------------
// 64 blocks; block b owns dst range [b*N/64,(b+1)*N/64) per node type. Every
// block streams ALL dst indices (L3-amortized) and counts/scatters only owned
// edges via LDS histograms/cursors. No global atomics, no memory-side RMW.

__global__ __launch_bounds__(1024)
void count_own(const int* __restrict__ dc, const int* __restrict__ dw,
               const int* __restrict__ dr,
               int* __restrict__ cntC, int* __restrict__ cntW, int* __restrict__ cntR,
               int E_, int NP_, int NA_) {
  const int b = blockIdx.x, t = threadIdx.x;
  const int loP = (int)((long)b * NP_ / 64), hiP = (int)((long)(b + 1) * NP_ / 64);
  const int loA = (int)((long)b * NA_ / 64), hiA = (int)((long)(b + 1) * NA_ / 64);
  const int nP = hiP - loP, nA = hiA - loA;
  __shared__ int hC[784], hW[784], hR[392];
  for (int i = t; i < 784; i += 1024) { hC[i] = 0; hW[i] = 0; }
  for (int i = t; i < 392; i += 1024) hR[i] = 0;
  __syncthreads();
  const int E4 = E_ & ~3;
  for (int i = t * 4; i + 3 < E_; i += 4096) {
    int4 d = *(const int4*)(dc + i);
    if (d.x >= loP && d.x < hiP) atomicAdd(&hC[d.x - loP], 1);
    if (d.y >= loP && d.y < hiP) atomicAdd(&hC[d.y - loP], 1);
    if (d.z >= loP && d.z < hiP) atomicAdd(&hC[d.z - loP], 1);
    if (d.w >= loP && d.w < hiP) atomicAdd(&hC[d.w - loP], 1);
  }
  for (int i = E4 + t; i < E_; i += 1024) { int d = dc[i]; if (d >= loP && d < hiP) atomicAdd(&hC[d - loP], 1); }
  for (int i = t * 4; i + 3 < E_; i += 4096) {
    int4 d = *(const int4*)(dw + i);
    if (d.x >= loP && d.x < hiP) atomicAdd(&hW[d.x - loP], 1);
    if (d.y >= loP && d.y < hiP) atomicAdd(&hW[d.y - loP], 1);
    if (d.z >= loP && d.z < hiP) atomicAdd(&hW[d.z - loP], 1);
    if (d.w >= loP && d.w < hiP) atomicAdd(&hW[d.w - loP], 1);
  }
  for (int i = E4 + t; i < E_; i += 1024) { int d = dw[i]; if (d >= loP && d < hiP) atomicAdd(&hW[d - loP], 1); }
  for (int i = t * 4; i + 3 < E_; i += 4096) {
    int4 d = *(const int4*)(dr + i);
    if (d.x >= loA && d.x < hiA) atomicAdd(&hR[d.x - loA], 1);
    if (d.y >= loA && d.y < hiA) atomicAdd(&hR[d.y - loA], 1);
    if (d.z >= loA && d.z < hiA) atomicAdd(&hR[d.z - loA], 1);
    if (d.w >= loA && d.w < hiA) atomicAdd(&hR[d.w - loA], 1);
  }
  for (int i = E4 + t; i < E_; i += 1024) { int d = dr[i]; if (d >= loA && d < hiA) atomicAdd(&hR[d - loA], 1); }
  __syncthreads();
  for (int i = t; i < nP; i += 1024) { cntC[loP + i] = hC[i]; cntW[loP + i] = hW[i]; }
  for (int i = t; i < nA; i += 1024) cntR[loA + i] = hR[i];
}

__global__ __launch_bounds__(1024)
void fill_own(const int* __restrict__ sc, const int* __restrict__ dc,
              const int* __restrict__ sw, const int* __restrict__ dw,
              const int* __restrict__ sr, const int* __restrict__ dr,
              const int* __restrict__ rpC, const int* __restrict__ rpW, const int* __restrict__ rpR,
              int* __restrict__ eC, int* __restrict__ eW, int* __restrict__ eR,
              int E_, int NP_, int NA_) {
  const int b = blockIdx.x, t = threadIdx.x;
  const int loP = (int)((long)b * NP_ / 64), hiP = (int)((long)(b + 1) * NP_ / 64);
  const int loA = (int)((long)b * NA_ / 64), hiA = (int)((long)(b + 1) * NA_ / 64);
  const int nP = hiP - loP, nA = hiA - loA;
  __shared__ int cC[784], cW[784], cR[392];
  for (int i = t; i < nP; i += 1024) { cC[i] = rpC[loP + i]; cW[i] = rpW[loP + i]; }
  for (int i = t; i < nA; i += 1024) cR[i] = rpR[loA + i];
  __syncthreads();
  const int E4 = E_ & ~3;
  for (int i = t * 4; i + 3 < E_; i += 4096) {
    int4 d = *(const int4*)(dc + i);
    if (d.x >= loP && d.x < hiP) { int p = atomicAdd(&cC[d.x - loP], 1); eC[p] = sc[i]; }
    if (d.y >= loP && d.y < hiP) { int p = atomicAdd(&cC[d.y - loP], 1); eC[p] = sc[i + 1]; }
    if (d.z >= loP && d.z < hiP) { int p = atomicAdd(&cC[d.z - loP], 1); eC[p] = sc[i + 2]; }
    if (d.w >= loP && d.w < hiP) { int p = atomicAdd(&cC[d.w - loP], 1); eC[p] = sc[i + 3]; }
  }
  for (int i = E4 + t; i < E_; i += 1024) { int d = dc[i]; if (d >= loP && d < hiP) { int p = atomicAdd(&cC[d - loP], 1); eC[p] = sc[i]; } }
  for (int i = t * 4; i + 3 < E_; i += 4096) {
    int4 d = *(const int4*)(dw + i);
    if (d.x >= loP && d.x < hiP) { int p = atomicAdd(&cW[d.x - loP], 1); eW[p] = sw[i]; }
    if (d.y >= loP && d.y < hiP) { int p = atomicAdd(&cW[d.y - loP], 1); eW[p] = sw[i + 1]; }
    if (d.z >= loP && d.z < hiP) { int p = atomicAdd(&cW[d.z - loP], 1); eW[p] = sw[i + 2]; }
    if (d.w >= loP && d.w < hiP) { int p = atomicAdd(&cW[d.w - loP], 1); eW[p] = sw[i + 3]; }
  }
  for (int i = E4 + t; i < E_; i += 1024) { int d = dw[i]; if (d >= loP && d < hiP) { int p = atomicAdd(&cW[d - loP], 1); eW[p] = sw[i]; } }
  for (int i = t * 4; i + 3 < E_; i += 4096) {
    int4 d = *(const int4*)(dr + i);
    if (d.x >= loA && d.x < hiA) { int p = atomicAdd(&cR[d.x - loA], 1); eR[p] = sr[i]; }
    if (d.y >= loA && d.y < hiA) { int p = atomicAdd(&cR[d.y - loA], 1); eR[p] = sr[i + 1]; }
    if (d.z >= loA && d.z < hiA) { int p = atomicAdd(&cR[d.z - loA], 1); eR[p] = sr[i + 2]; }
    if (d.w >= loA && d.w < hiA) { int p = atomicAdd(&cR[d.w - loA], 1); eR[p] = sr[i + 3]; }
  }
  for (int i = E4 + t; i < E_; i += 1024) { int d = dr[i]; if (d >= loA && d < hiA) { int p = atomicAdd(&cR[d - loA], 1); eR[p] = sr[i]; } }
}

// ---------------- hierarchical exclusive scan (counts -> rowptr + invdeg) ----------------

__global__ __launch_bounds__(256)
void scan_pass1(const int* __restrict__ cC, int nC,
                const int* __restrict__ cW, int nW,
                const int* __restrict__ cR, int nR,
                int* __restrict__ bs, int nbC, int nbW) {
  const int b = blockIdx.x;
  const int* cnt; int n, lb, bsoff;
  if (b < nbC)            { cnt = cC; n = nC; lb = b;             bsoff = 0; }
  else if (b < nbC + nbW) { cnt = cW; n = nW; lb = b - nbC;       bsoff = nbC; }
  else                    { cnt = cR; n = nR; lb = b - nbC - nbW; bsoff = nbC + nbW; }
  const int t = threadIdx.x, lane = t & 63, wid = t >> 6;
  const int base = lb * 1024 + t * 4;
  int c0 = 0, c1 = 0, c2 = 0, c3 = 0;
  if (base + 3 < n) { int4 q = *(const int4*)(cnt + base); c0 = q.x; c1 = q.y; c2 = q.z; c3 = q.w; }
  else {
    if (base < n)     c0 = cnt[base];
    if (base + 1 < n) c1 = cnt[base + 1];
    if (base + 2 < n) c2 = cnt[base + 2];
  }
  int v = c0 + c1 + c2 + c3;
  for (int off = 32; off; off >>= 1) v += __shfl_xor(v, off, 64);
  __shared__ int wsum[4];
  if (lane == 0) wsum[wid] = v;
  __syncthreads();
  if (t == 0) bs[bsoff + lb] = wsum[0] + wsum[1] + wsum[2] + wsum[3];
}

__global__ __launch_bounds__(256)
void scan_pass2(const int* __restrict__ cC, int* __restrict__ rC, float* __restrict__ vC, int nC,
                const int* __restrict__ cW, int* __restrict__ rW, float* __restrict__ vW, int nW,
                const int* __restrict__ cR, int* __restrict__ rR, float* __restrict__ vR, int nR,
                const int* __restrict__ bs, int nbC, int nbW, int nbR) {
  const int b = blockIdx.x;
  const int* cnt; int* rp; float* inv; int n, lb, bsoff, nb;
  if (b < nbC)            { cnt = cC; rp = rC; inv = vC; n = nC; lb = b;             bsoff = 0;         nb = nbC; }
  else if (b < nbC + nbW) { cnt = cW; rp = rW; inv = vW; n = nW; lb = b - nbC;       bsoff = nbC;       nb = nbW; }
  else                    { cnt = cR; rp = rR; inv = vR; n = nR; lb = b - nbC - nbW; bsoff = nbC + nbW; nb = nbR; }
  const int t = threadIdx.x, lane = t & 63, wid = t >> 6;
  __shared__ int sh_off;
  __shared__ int wsum[4];
  if (wid == 0) {
    int v = (lane < lb) ? bs[bsoff + lane] : 0;
    for (int off = 32; off; off >>= 1) v += __shfl_xor(v, off, 64);
    if (lane == 0) sh_off = v;
  }
  const int base = lb * 1024 + t * 4;
  int c0 = 0, c1 = 0, c2 = 0, c3 = 0;
  if (base + 3 < n) { int4 q = *(const int4*)(cnt + base); c0 = q.x; c1 = q.y; c2 = q.z; c3 = q.w; }
  else {
    if (base < n)     c0 = cnt[base];
    if (base + 1 < n) c1 = cnt[base + 1];
    if (base + 2 < n) c2 = cnt[base + 2];
  }
  const int tsum = c0 + c1 + c2 + c3;
  int isc = tsum;
  for (int off = 1; off < 64; off <<= 1) {
    int y = __shfl_up(isc, off, 64);
    if (lane >= off) isc += y;
  }
  if (lane == 63) wsum[wid] = isc;
  __syncthreads();
  int woff = sh_off;
  for (int w = 0; w < wid; ++w) woff += wsum[w];
  const int e = woff + isc - tsum;
  const int ex0 = e, ex1 = e + c0, ex2 = e + c0 + c1, ex3 = e + c0 + c1 + c2;
  if (base + 3 < n) {
    *(int4*)(rp + base) = make_int4(ex0, ex1, ex2, ex3);
    *(float4*)(inv + base) = make_float4(1.f / (c0 > 1 ? c0 : 1), 1.f / (c1 > 1 ? c1 : 1),
                                         1.f / (c2 > 1 ? c2 : 1), 1.f / (c3 > 1 ? c3 : 1));
  } else {
    if (base < n)     { rp[base] = ex0;     inv[base] = 1.f / (c0 > 1 ? c0 : 1); }
    if (base + 1 < n) { rp[base + 1] = ex1; inv[base + 1] = 1.f / (c1 > 1 ? c1 : 1); }
    if (base + 2 < n) { rp[base + 2] = ex2; inv[base + 2] = 1.f / (c2 > 1 ? c2 : 1); }
  }
  if (lb == nb - 1 && t == 255) rp[n] = woff + isc;
}

// ---------------- prep: W^T bf16 + biases, and f32->bf16 feature convert ----------------

__global__ __launch_bounds__(256)
void prep_all(const float* Wl1c, const float* bl1c, const float* Wr1c,
              const float* Wl1w, const float* bl1w, const float* Wr1w,
              const float* Wl1r, const float* bl1r, const float* Wr1r,
              const float* Wl2c, const float* bl2c, const float* Wr2c,
              const float* Wl2w, const float* bl2w, const float* Wr2w,
              const float* Wl2r, const float* bl2r, const float* Wr2r,
              unsigned short* WT, float* bias,
              const float4* __restrict__ xp, unsigned short* __restrict__ oxp, long np4,
              const float4* __restrict__ xa, unsigned short* __restrict__ oxa, long na4) {
  const int t = threadIdx.x;
  if (blockIdx.x >= 1024) {  // feature convert
    long i = (long)(blockIdx.x - 1024) * 256 + t;
    const long tot = np4 + na4;
    const long stride = (long)(gridDim.x - 1024) * 256;
    for (; i < tot; i += stride) {
      const float4* src; unsigned short* dst; long j;
      if (i < np4) { src = xp; dst = oxp; j = i; } else { src = xa; dst = oxa; j = i - np4; }
      float4 v = src[j];
      ushort4 o;
      o.x = f2bf(v.x); o.y = f2bf(v.y); o.z = f2bf(v.z); o.w = f2bf(v.w);
      *(ushort4*)(dst + j * 4) = o;
    }
    return;
  }
  const int mat = blockIdx.x >> 8;
  const int nn = blockIdx.x & 255;
  if (mat == 0) {  // P1: K=640 = [Wl1c(256); Wl1w(128); Wr1c+Wr1w(256)]
    unsigned short* out = WT + (size_t)nn * 640;
    for (int k = t; k < 640; k += 256) {
      float v;
      if (k < 256)      v = Wl1c[k * 256 + nn];
      else if (k < 384) v = Wl1w[(k - 256) * 256 + nn];
      else              v = Wr1c[(k - 384) * 256 + nn] + Wr1w[(k - 384) * 256 + nn];
      out[k] = f2bf(v);
    }
    if (t == 0) bias[nn] = bl1c[nn] + bl1w[nn];
  } else if (mat == 1) {  // A1: K=384
    unsigned short* out = WT + (size_t)256 * 640 + (size_t)nn * 384;
    for (int k = t; k < 384; k += 256) {
      float v = (k < 256) ? Wl1r[k * 256 + nn] : Wr1r[(k - 256) * 256 + nn];
      out[k] = f2bf(v);
    }
    if (t == 0) bias[256 + nn] = bl1r[nn];
  } else if (mat == 2) {  // P2: K=768
    unsigned short* out = WT + (size_t)256 * (640 + 384) + (size_t)nn * 768;
    for (int k = t; k < 768; k += 256) {
      float v;
      if (k < 256)      v = Wl2c[k * 256 + nn];
      else if (k < 512) v = Wl2w[(k - 256) * 256 + nn];
      else              v = Wr2c[(k - 512) * 256 + nn] + Wr2w[(k - 512) * 256 + nn];
      out[k] = f2bf(v);
    }
    if (t == 0) bias[512 + nn] = bl2c[nn] + bl2w[nn];
  } else {  // A2: K=512
    unsigned short* out = WT + (size_t)256 * (640 + 384 + 768) + (size_t)nn * 512;
    for (int k = t; k < 512; k += 256) {
      float v = (k < 256) ? Wl2r[k * 256 + nn] : Wr2r[(k - 256) * 256 + nn];
      out[k] = f2bf(v);
    }
    if (t == 0) bias[768 + nn] = bl2r[nn];
  }
}

// ---------------- aggregation: wave per node, 8-row batches in flight ----------------

template <int D>
DEVFN void agg_node(const unsigned short* __restrict__ feat, const int* __restrict__ es,
                    int e0, int e1, float sc, unsigned short* __restrict__ outrow, int lane) {
  if constexpr (D == 256) {
    const unsigned short* f = feat + lane * 4;
    float a0 = 0, a1 = 0, a2 = 0, a3 = 0;
    int e = e0;
    for (; e + 7 < e1; e += 8) {
      int s0 = es[e], s1 = es[e + 1], s2 = es[e + 2], s3 = es[e + 3];
      int s4 = es[e + 4], s5 = es[e + 5], s6 = es[e + 6], s7 = es[e + 7];
      ushort4 v0 = *(const ushort4*)(f + (size_t)s0 * 256);
      ushort4 v1 = *(const ushort4*)(f + (size_t)s1 * 256);
      ushort4 v2 = *(const ushort4*)(f + (size_t)s2 * 256);
      ushort4 v3 = *(const ushort4*)(f + (size_t)s3 * 256);
      ushort4 v4 = *(const ushort4*)(f + (size_t)s4 * 256);
      ushort4 v5 = *(const ushort4*)(f + (size_t)s5 * 256);
      ushort4 v6 = *(const ushort4*)(f + (size_t)s6 * 256);
      ushort4 v7 = *(const ushort4*)(f + (size_t)s7 * 256);
      a0 += ((bf2f(v0.x) + bf2f(v1.x)) + (bf2f(v2.x) + bf2f(v3.x))) +
            ((bf2f(v4.x) + bf2f(v5.x)) + (bf2f(v6.x) + bf2f(v7.x)));
      a1 += ((bf2f(v0.y) + bf2f(v1.y)) + (bf2f(v2.y) + bf2f(v3.y))) +
            ((bf2f(v4.y) + bf2f(v5.y)) + (bf2f(v6.y) + bf2f(v7.y)));
      a2 += ((bf2f(v0.z) + bf2f(v1.z)) + (bf2f(v2.z) + bf2f(v3.z))) +
            ((bf2f(v4.z) + bf2f(v5.z)) + (bf2f(v6.z) + bf2f(v7.z)));
      a3 += ((bf2f(v0.w) + bf2f(v1.w)) + (bf2f(v2.w) + bf2f(v3.w))) +
            ((bf2f(v4.w) + bf2f(v5.w)) + (bf2f(v6.w) + bf2f(v7.w)));
    }
    for (; e + 3 < e1; e += 4) {
      int s0 = es[e], s1 = es[e + 1], s2 = es[e + 2], s3 = es[e + 3];
      ushort4 v0 = *(const ushort4*)(f + (size_t)s0 * 256);
      ushort4 v1 = *(const ushort4*)(f + (size_t)s1 * 256);
      ushort4 v2 = *(const ushort4*)(f + (size_t)s2 * 256);
      ushort4 v3 = *(const ushort4*)(f + (size_t)s3 * 256);
      a0 += (bf2f(v0.x) + bf2f(v1.x)) + (bf2f(v2.x) + bf2f(v3.x));
      a1 += (bf2f(v0.y) + bf2f(v1.y)) + (bf2f(v2.y) + bf2f(v3.y));
      a2 += (bf2f(v0.z) + bf2f(v1.z)) + (bf2f(v2.z) + bf2f(v3.z));
      a3 += (bf2f(v0.w) + bf2f(v1.w)) + (bf2f(v2.w) + bf2f(v3.w));
    }
    for (; e < e1; ++e) {
      int s0 = es[e];
      ushort4 v0 = *(const ushort4*)(f + (size_t)s0 * 256);
      a0 += bf2f(v0.x); a1 += bf2f(v0.y); a2 += bf2f(v0.z); a3 += bf2f(v0.w);
    }
    ushort4 o;
    o.x = f2bf(a0 * sc); o.y = f2bf(a1 * sc); o.z = f2bf(a2 * sc); o.w = f2bf(a3 * sc);
    *(ushort4*)(outrow + lane * 4) = o;
  } else {
    const unsigned short* f = feat + lane * 2;
    float a0 = 0, a1 = 0;
    int e = e0;
    for (; e + 7 < e1; e += 8) {
      int s0 = es[e], s1 = es[e + 1], s2 = es[e + 2], s3 = es[e + 3];
      int s4 = es[e + 4], s5 = es[e + 5], s6 = es[e + 6], s7 = es[e + 7];
      ushort2 v0 = *(const ushort2*)(f + (size_t)s0 * 128);
      ushort2 v1 = *(const ushort2*)(f + (size_t)s1 * 128);
      ushort2 v2 = *(const ushort2*)(f + (size_t)s2 * 128);
      ushort2 v3 = *(const ushort2*)(f + (size_t)s3 * 128);
      ushort2 v4 = *(const ushort2*)(f + (size_t)s4 * 128);
      ushort2 v5 = *(const ushort2*)(f + (size_t)s5 * 128);
      ushort2 v6 = *(const ushort2*)(f + (size_t)s6 * 128);
      ushort2 v7 = *(const ushort2*)(f + (size_t)s7 * 128);
      a0 += ((bf2f(v0.x) + bf2f(v1.x)) + (bf2f(v2.x) + bf2f(v3.x))) +
            ((bf2f(v4.x) + bf2f(v5.x)) + (bf2f(v6.x) + bf2f(v7.x)));
      a1 += ((bf2f(v0.y) + bf2f(v1.y)) + (bf2f(v2.y) + bf2f(v3.y))) +
            ((bf2f(v4.y) + bf2f(v5.y)) + (bf2f(v6.y) + bf2f(v7.y)));
    }
    for (; e + 3 < e1; e += 4) {
      int s0 = es[e], s1 = es[e + 1], s2 = es[e + 2], s3 = es[e + 3];
      ushort2 v0 = *(const ushort2*)(f + (size_t)s0 * 128);
      ushort2 v1 = *(const ushort2*)(f + (size_t)s1 * 128);
      ushort2 v2 = *(const ushort2*)(f + (size_t)s2 * 128);
      ushort2 v3 = *(const ushort2*)(f + (size_t)s3 * 128);
      a0 += (bf2f(v0.x) + bf2f(v1.x)) + (bf2f(v2.x) + bf2f(v3.x));
      a1 += (bf2f(v0.y) + bf2f(v1.y)) + (bf2f(v2.y) + bf2f(v3.y));
    }
    for (; e < e1; ++e) {
      int s0 = es[e];
      ushort2 v0 = *(const ushort2*)(f + (size_t)s0 * 128);
      a0 += bf2f(v0.x); a1 += bf2f(v0.y);
    }
    ushort2 o; o.x = f2bf(a0 * sc); o.y = f2bf(a1 * sc);
    *(ushort2*)(outrow + lane * 2) = o;
  }
}

struct AggJob {
  const unsigned short* feat; const int* rp; const int* es; const float* inv;
  unsigned short* out; int n;
};

// layer 1: jobs j0 (D256), j1 (D256), j2 (D128)
__global__ __launch_bounds__(256)
void agg_l1(AggJob j0, AggJob j1, AggJob j2, int b0, int b1) {
  const int b = blockIdx.x;
  const AggJob* j; int lb; bool d128 = false;
  if (b < b0)           { j = &j0; lb = b; }
  else if (b < b0 + b1) { j = &j1; lb = b - b0; }
  else                  { j = &j2; lb = b - b0 - b1; d128 = true; }
  const int node = lb * 4 + (threadIdx.x >> 6);
  const int lane = threadIdx.x & 63;
  if (node >= j->n) return;
  const int e0 = j->rp[node], e1 = j->rp[node + 1];
  const float sc = j->inv[node];
  if (!d128) agg_node<256>(j->feat, j->es, e0, e1, sc, j->out + (size_t)node * 256, lane);
  else       agg_node<128>(j->feat, j->es, e0, e1, sc, j->out + (size_t)node * 128, lane);
}

// layer 2: all D256
__global__ __launch_bounds__(256)
void agg_l2(AggJob j0, AggJob j1, AggJob j2, int b0, int b1) {
  const int b = blockIdx.x;
  const AggJob* j; int lb;
  if (b < b0)           { j = &j0; lb = b; }
  else if (b < b0 + b1) { j = &j1; lb = b - b0; }
  else                  { j = &j2; lb = b - b0 - b1; }
  const int node = lb * 4 + (threadIdx.x >> 6);
  const int lane = threadIdx.x & 63;
  if (node >= j->n) return;
  const int e0 = j->rp[node], e1 = j->rp[node + 1];
  const float sc = j->inv[node];
  agg_node<256>(j->feat, j->es, e0, e1, sc, j->out + (size_t)node * 256, lane);
}

// ---------------- segmented-A bf16 MFMA GEMM: C[M x 256] = [segA] @ W^T + bias ----------------

struct Segs {
  const unsigned short *p0, *p1, *p2;
  int ld0, ld1, ld2;
  int ke0, ke1;  // segment end k-offsets (elements); seg2 ends at KTOT
};

template <int KTOT, bool RELU, bool OBF16>
__global__ __launch_bounds__(256, 2)
void gemm_sage(Segs sg, const unsigned short* __restrict__ Wt,
               const float* __restrict__ bias, void* __restrict__ outp, int M) {
  __shared__ alignas(16) unsigned short lsA[128 * 64];
  __shared__ alignas(16) unsigned short lsB[128 * 64];

  const int tid = threadIdx.x;
  const int lane = tid & 63;
  const int wave = tid >> 6;
  const int wr = wave >> 1, wc = wave & 1;
  const int mt = blockIdx.x >> 1, nt = blockIdx.x & 1;

  const floatx4 fzero = {0.f, 0.f, 0.f, 0.f};
  floatx4 acc[4][4];
#pragma unroll
  for (int m = 0; m < 4; ++m)
#pragma unroll
    for (int n = 0; n < 4; ++n) acc[m][n] = fzero;

  const int srow = tid >> 3;        // 0..31: tile row chunk per staging stmt
  const int scol = (tid & 7) * 8;   // element offset within 64-wide k-tile (16B)
  const int arow = wr * 64 + (lane & 15);
  const int brow = wc * 64 + (lane & 15);
  const int kq = (lane >> 4) * 8;

  constexpr int KT = KTOT / 64;
#pragma unroll 1
  for (int kt = 0; kt < KT; ++kt) {
    const int k0 = kt * 64;
    const unsigned short* sp; int sld, skb;
    if (k0 < sg.ke0)      { sp = sg.p0; sld = sg.ld0; skb = 0; }
    else if (k0 < sg.ke1) { sp = sg.p1; sld = sg.ld1; skb = sg.ke0; }
    else                  { sp = sg.p2; sld = sg.ld2; skb = sg.ke1; }

#pragma unroll
    for (int s = 0; s < 4; ++s) {
      int r = s * 32 + srow;
      int g = mt * 128 + r; g = g < M ? g : M - 1;
      gload_lds16(sp + (size_t)g * sld + (k0 - skb) + scol, lsA + r * 64 + scol);
    }
#pragma unroll
    for (int s = 0; s < 4; ++s) {
      int r = s * 32 + srow;
      gload_lds16(Wt + (size_t)(nt * 128 + r) * KTOT + k0 + scol, lsB + r * 64 + scol);
    }
    __syncthreads();  // drain global_load_lds + barrier

    shortx8 af[2][4], bq[2][4];
#pragma unroll
    for (int kk = 0; kk < 2; ++kk)
#pragma unroll
      for (int i = 0; i < 4; ++i) {
        af[kk][i] = *(const shortx8*)(lsA + (arow + i * 16) * 64 + kk * 32 + kq);
        bq[kk][i] = *(const shortx8*)(lsB + (brow + i * 16) * 64 + kk * 32 + kq);
      }
#pragma unroll
    for (int m = 0; m < 4; ++m)
#pragma unroll
      for (int n = 0; n < 4; ++n) {
        acc[m][n] = __builtin_amdgcn_mfma_f32_16x16x32_bf16(af[0][m], bq[0][n], acc[m][n], 0, 0, 0);
        acc[m][n] = __builtin_amdgcn_mfma_f32_16x16x32_bf16(af[1][m], bq[1][n], acc[m][n], 0, 0, 0);
      }
    __syncthreads();  // protect LDS before next stage
  }

  const int lr = (lane >> 4) * 4;
  const int lc = lane & 15;
  const int rb = mt * 128 + wr * 64;
  const int cb = nt * 128 + wc * 64;
#pragma unroll
  for (int m = 0; m < 4; ++m) {
#pragma unroll
    for (int j = 0; j < 4; ++j) {
      const int row = rb + m * 16 + lr + j;
      if (row < M) {
#pragma unroll
        for (int n = 0; n < 4; ++n) {
          const int col = cb + n * 16 + lc;
          float v = acc[m][n][j] + bias[col];
          if (RELU) v = v > 0.f ? v : 0.f;
          if (OBF16) ((unsigned short*)outp)[(size_t)row * 256 + col] = f2bf(v);
          else       ((float*)outp)[(size_t)row * 256 + col] = v;
        }
      }
    }
  }
}

// ---------------- host ----------------

extern "C" void kernel_launch(void* const* d_in, const int* in_sizes, int n_in,
                              void* d_out, int out_size, void* d_ws, size_t ws_size,
                              hipStream_t stream) {
  const float* x_paper = (const float*)d_in[0];
  const float* x_author = (const float*)d_in[1];
  const int* cites_src = (const int*)d_in[2];
  const int* cites_dst = (const int*)d_in[3];
  const int* writes_src = (const int*)d_in[4];
  const int* writes_dst = (const int*)d_in[5];
  const int* rev_src = (const int*)d_in[6];
  const int* rev_dst = (const int*)d_in[7];
  const float* Wl1c = (const float*)d_in[8];  const float* bl1c = (const float*)d_in[9];  const float* Wr1c = (const float*)d_in[10];
  const float* Wl1w = (const float*)d_in[11]; const float* bl1w = (const float*)d_in[12]; const float* Wr1w = (const float*)d_in[13];
  const float* Wl1r = (const float*)d_in[14]; const float* bl1r = (const float*)d_in[15]; const float* Wr1r = (const float*)d_in[16];
  const float* Wl2c = (const float*)d_in[17]; const float* bl2c = (const float*)d_in[18]; const float* Wr2c = (const float*)d_in[19];
  const float* Wl2w = (const float*)d_in[20]; const float* bl2w = (const float*)d_in[21]; const float* Wr2w = (const float*)d_in[22];
  const float* Wl2r = (const float*)d_in[23]; const float* bl2r = (const float*)d_in[24]; const float* Wr2r = (const float*)d_in[25];

  const int NP = in_sizes[0] / 256;  // 50000
  const int NA = in_sizes[1] / 128;  // 25000
  const int E = in_sizes[2];         // 400000

  char* w = (char*)d_ws;
  auto alloc = [&](size_t bytes) -> char* {
    char* p = w;
    w += (bytes + 255) & ~(size_t)255;
    return p;
  };

  unsigned short* xpb = (unsigned short*)alloc((size_t)NP * 256 * 2);
  unsigned short* xab = (unsigned short*)alloc((size_t)NA * 128 * 2);
  unsigned short* mA  = (unsigned short*)alloc((size_t)NP * 256 * 2);
  unsigned short* mB  = (unsigned short*)alloc((size_t)NP * 256 * 2);
  unsigned short* mC  = (unsigned short*)alloc((size_t)NA * 256 * 2);
  unsigned short* p1b = (unsigned short*)alloc((size_t)NP * 256 * 2);
  unsigned short* a1b = (unsigned short*)alloc((size_t)NA * 256 * 2);
  unsigned short* WT  = (unsigned short*)alloc((size_t)2304 * 256 * 2);
  float* bias = (float*)alloc(4 * 256 * 4);
  int* cntC = (int*)alloc((size_t)NP * 4);
  int* cntW = (int*)alloc((size_t)NP * 4);
  int* cntR = (int*)alloc((size_t)NA * 4);
  int* rpC = (int*)alloc((size_t)(NP + 1) * 4);
  int* rpW = (int*)alloc((size_t)(NP + 1) * 4);
  int* rpR = (int*)alloc((size_t)(NA + 1) * 4);
  float* invC = (float*)alloc((size_t)NP * 4);
  float* invW = (float*)alloc((size_t)NP * 4);
  float* invR = (float*)alloc((size_t)NA * 4);
  int* esC = (int*)alloc((size_t)E * 4);
  int* esW = (int*)alloc((size_t)E * 4);
  int* esR = (int*)alloc((size_t)E * 4);
  int* bsums = (int*)alloc(256 * 4);

  // weights + feature converts (one kernel)
  prep_all<<<2560, 256, 0, stream>>>(Wl1c, bl1c, Wr1c, Wl1w, bl1w, Wr1w, Wl1r, bl1r, Wr1r,
                                     Wl2c, bl2c, Wr2c, Wl2w, bl2w, Wr2w, Wl2r, bl2r, Wr2r,
                                     WT, bias,
                                     (const float4*)x_paper, xpb, (long)NP * 256 / 4,
                                     (const float4*)x_author, xab, (long)NA * 128 / 4);

  // CSR build (ownership-partitioned, LDS-only atomics)
  const int nbC = (NP + 1023) / 1024, nbW = (NP + 1023) / 1024, nbR = (NA + 1023) / 1024;
  count_own<<<64, 1024, 0, stream>>>(cites_dst, writes_dst, rev_dst, cntC, cntW, cntR, E, NP, NA);
  scan_pass1<<<nbC + nbW + nbR, 256, 0, stream>>>(cntC, NP, cntW, NP, cntR, NA, bsums, nbC, nbW);
  scan_pass2<<<nbC + nbW + nbR, 256, 0, stream>>>(cntC, rpC, invC, NP, cntW, rpW, invW, NP,
                                                  cntR, rpR, invR, NA, bsums, nbC, nbW, nbR);
  fill_own<<<64, 1024, 0, stream>>>(cites_src, cites_dst, writes_src, writes_dst, rev_src, rev_dst,
                                    rpC, rpW, rpR, esC, esW, esR, E, NP, NA);

  // layer-1 aggregation (one launch)
  {
    AggJob j0{xpb, rpC, esC, invC, mA, NP};   // D256
    AggJob j1{xpb, rpR, esR, invR, mC, NA};   // D256
    AggJob j2{xab, rpW, esW, invW, mB, NP};   // D128
    const int b0 = (NP + 3) / 4, b1 = (NA + 3) / 4, b2 = (NP + 3) / 4;
    agg_l1<<<b0 + b1 + b2, 256, 0, stream>>>(j0, j1, j2, b0, b1);
  }

  // layer-1 GEMMs (relu, bf16 out)
  {
    Segs s; s.p0 = mA; s.ld0 = 256; s.ke0 = 256;
    s.p1 = mB; s.ld1 = 128; s.ke1 = 384;
    s.p2 = xpb; s.ld2 = 256;
    gemm_sage<640, true, true><<<((NP + 127) / 128) * 2, 256, 0, stream>>>(s, WT, bias, p1b, NP);
  }
  {
    Segs s; s.p0 = mC; s.ld0 = 256; s.ke0 = 256;
    s.p1 = xab; s.ld1 = 128; s.ke1 = 384;
    s.p2 = xab; s.ld2 = 128;
    gemm_sage<384, true, true><<<((NA + 127) / 128) * 2, 256, 0, stream>>>(
        s, WT + (size_t)256 * 640, bias + 256, a1b, NA);
  }

  // layer-2 aggregation (one launch, reuse CSR)
  {
    AggJob j0{p1b, rpC, esC, invC, mA, NP};
    AggJob j1{a1b, rpW, esW, invW, mB, NP};
    AggJob j2{p1b, rpR, esR, invR, mC, NA};
    const int b0 = (NP + 3) / 4, b1 = (NP + 3) / 4, b2 = (NA + 3) / 4;
    agg_l2<<<b0 + b1 + b2, 256, 0, stream>>>(j0, j1, j2, b0, b1);
  }

  // layer-2 GEMMs (no relu, f32 out -> d_out)
  {
    Segs s; s.p0 = mA; s.ld0 = 256; s.ke0 = 256;
    s.p1 = mB; s.ld1 = 256; s.ke1 = 512;
    s.p2 = p1b; s.ld2 = 256;
    gemm_sage<768, false, false><<<((NP + 127) / 128) * 2, 256, 0, stream>>>(
        s, WT + (size_t)256 * (640 + 384), bias + 512, d_out, NP);
  }
  {
    Segs s; s.p0 = mC; s.ld0 = 256; s.ke0 = 256;
    s.p1 = a1b; s.ld1 = 256; s.ke1 = 512;
    s.p2 = a1b; s.ld2 = 256;
    gemm_sage<512, false, false><<<((NA + 127) / 128) * 2, 256, 0, stream>>>(
        s, WT + (size_t)256 * (640 + 384 + 768), bias + 768,
        (float*)d_out + (size_t)NP * 256, NA);
  }
}